// Round 1
// baseline (103.743 us; speedup 1.0000x reference)
//
#include <hip/hip_runtime.h>

#define NN 2048
#define DD 1024
#define CC 10
#define RS 16          // padded row stride (floats) -> 64B-aligned rows
#define ICH 16         // i's per pair_kernel block
#define GCE_Q_ 0.7f
#define EPS_ 1e-8f

// workspace layout (float offsets)
#define OFF_EAc 0        // [2048][16] exp(Ac - mAc)
#define OFF_EAb 32768    // [2048][16] exp(Ab - mAb)
#define OFF_Abr 65536    // [2048][16] raw Ab rows (for y[j] gather, per-lane col)
#define OFF_EBc 98304    // [2048][16]
#define OFF_EBb 131072   // [2048][16]
#define OFF_BcT 163840   // [10][2048] raw Bc TRANSPOSED (uniform col, per-lane j)
#define OFF_BbT 184320   // [10][2048] raw Bb TRANSPOSED
#define OFF_IA  204800   // [2048][4] {mAc, mAb, Ac[i,yi], Ab[i,yi]}
#define OFF_JS  212992   // [2048][4] {mBc, mBb, Bb[j,yj], pad}
// total = 221184 floats = 884736 bytes

// ---------------------------------------------------------------------------
// Kernel 1: four skinny GEMMs ([4096 rows] x D=1024 -> 20 outputs/row) with
// W in registers, plus softmax-prep epilogue. Rows 0..2047 = z_c (bias folded
// in), rows 2048..4095 = z_b (no bias).
// ---------------------------------------------------------------------------
__global__ __launch_bounds__(256) void prep_kernel(
    const float* __restrict__ z_c, const float* __restrict__ z_b,
    const float* __restrict__ Wc, const float* __restrict__ bc,
    const float* __restrict__ Wb, const float* __restrict__ bb,
    const int* __restrict__ y, float* __restrict__ ws)
{
  const int t = threadIdx.x;
  const int d0 = t * 4;

  // W fragments in registers: 20 x float4 = 80 VGPRs
  float4 wcr[CC], wbr[CC];
#pragma unroll
  for (int k = 0; k < CC; ++k) {
    wcr[k] = *(const float4*)(Wc + k * DD + d0);
    wbr[k] = *(const float4*)(Wb + k * DD + d0);
  }

  const int rowBase = blockIdx.x * 8;          // 512 blocks x 8 rows = 4096
  const bool isB = rowBase >= NN;
  const float* __restrict__ z = isB ? z_b : z_c;
  const int r0 = isB ? (rowBase - NN) : rowBase;

  __shared__ float red[8][64][20];  // 40 KB: 64 partials (4-lane groups) x 20 outputs
  __shared__ float sums[8][20];

  float4 zv = *(const float4*)(z + (size_t)r0 * DD + d0);
  for (int rr = 0; rr < 8; ++rr) {
    float4 zn = zv;
    if (rr < 7) zn = *(const float4*)(z + (size_t)(r0 + rr + 1) * DD + d0);

    float pc[CC], pb[CC];
#pragma unroll
    for (int k = 0; k < CC; ++k) {
      pc[k] = fmaf(zv.x, wcr[k].x, fmaf(zv.y, wcr[k].y, fmaf(zv.z, wcr[k].z, zv.w * wcr[k].w)));
      pb[k] = fmaf(zv.x, wbr[k].x, fmaf(zv.y, wbr[k].y, fmaf(zv.z, wbr[k].z, zv.w * wbr[k].w)));
    }
    // 2-step butterfly -> 4-lane group sums (lanes t%4==0 hold them)
#pragma unroll
    for (int m = 1; m <= 2; m <<= 1) {
#pragma unroll
      for (int k = 0; k < CC; ++k) {
        pc[k] += __shfl_xor(pc[k], m, 64);
        pb[k] += __shfl_xor(pb[k], m, 64);
      }
    }
    if ((t & 3) == 0) {
      float* dst = &red[rr][t >> 2][0];   // 80B stride, 16B aligned -> b128 stores
#pragma unroll
      for (int k = 0; k < CC; ++k) { dst[k] = pc[k]; dst[CC + k] = pb[k]; }
    }
    zv = zn;
  }
  __syncthreads();

  // phase 2: 160 threads, one (row, output) each: reduce the 64 partials
  if (t < 160) {
    const int rr = t / 20;
    const int kk = t % 20;
    float s0 = 0.f, s1 = 0.f, s2 = 0.f, s3 = 0.f;
#pragma unroll
    for (int p = 0; p < 64; p += 4) {
      s0 += red[rr][p + 0][kk];
      s1 += red[rr][p + 1][kk];
      s2 += red[rr][p + 2][kk];
      s3 += red[rr][p + 3][kk];
    }
    float s = (s0 + s1) + (s2 + s3);
    if (!isB) s += (kk < CC) ? bc[kk] : bb[kk - CC];  // fold bias into i-side
    sums[rr][kk] = s;
  }
  __syncthreads();

  // phase 3: per-row softmax prep + stores
  if (t < 160) {
    const int rr = t / 20;
    const int kk = t % 20;
    const int head = kk / CC;
    const int k = kk % CC;
    const int row = r0 + rr;
    float m = -1e30f;
#pragma unroll
    for (int q = 0; q < CC; ++q) m = fmaxf(m, sums[rr][head * CC + q]);
    const float v = sums[rr][kk];
    const float e = __expf(v - m);
    if (!isB) {
      if (head == 0) {
        ws[OFF_EAc + row * RS + k] = e;
      } else {
        ws[OFF_EAb + row * RS + k] = e;
        ws[OFF_Abr + row * RS + k] = v;        // raw Ab row for y[j] gather
      }
    } else {
      if (head == 0) {
        ws[OFF_EBc + row * RS + k] = e;
        ws[OFF_BcT + k * NN + row] = v;        // transposed raw Bc
      } else {
        ws[OFF_EBb + row * RS + k] = e;
        ws[OFF_BbT + k * NN + row] = v;        // transposed raw Bb
      }
    }
    if (kk == 0) {
      const int yr = y[row];
      float m0 = -1e30f, m1 = -1e30f;
#pragma unroll
      for (int q = 0; q < CC; ++q) {
        m0 = fmaxf(m0, sums[rr][q]);
        m1 = fmaxf(m1, sums[rr][CC + q]);
      }
      float4 v4;
      if (!isB) {
        v4 = make_float4(m0, m1, sums[rr][yr], sums[rr][CC + yr]); // mAc,mAb,Acy,Aby
        *(float4*)(ws + OFF_IA + row * 4) = v4;
      } else {
        v4 = make_float4(m0, m1, sums[rr][CC + yr], 0.f);          // mBc,mBb,Bby
        *(float4*)(ws + OFF_JS + row * 4) = v4;
      }
    }
  }
}

// ---------------------------------------------------------------------------
// Kernel 2: per-pair loss. Thread owns one j (j-side exp rows in VGPRs),
// loops over ICH uniform i's (i-side rows via scalar loads). Coalesced out.
// ---------------------------------------------------------------------------
__global__ __launch_bounds__(256) void pair_kernel(
    const float* __restrict__ ws, const int* __restrict__ y,
    float* __restrict__ out)
{
  const float* __restrict__ EAc = ws + OFF_EAc;
  const float* __restrict__ EAb = ws + OFF_EAb;
  const float* __restrict__ Abr = ws + OFF_Abr;
  const float* __restrict__ EBc = ws + OFF_EBc;
  const float* __restrict__ EBb = ws + OFF_EBb;
  const float* __restrict__ BcT = ws + OFF_BcT;
  const float* __restrict__ BbT = ws + OFF_BbT;
  const float* __restrict__ IA  = ws + OFF_IA;
  const float* __restrict__ JS  = ws + OFF_JS;

  const int j = blockIdx.x * 256 + threadIdx.x;

  float ebc[CC], ebb[CC];
#pragma unroll
  for (int k = 0; k < CC; ++k) {
    ebc[k] = EBc[j * RS + k];
    ebb[k] = EBb[j * RS + k];
  }
  const float4 js = *(const float4*)(JS + j * 4);
  const float mBc = js.x, mBb = js.y, Bby = js.z;
  const int yj = y[j];

  const int iBase = __builtin_amdgcn_readfirstlane(blockIdx.y * ICH);
  for (int ii = 0; ii < ICH; ++ii) {
    const int i = iBase + ii;                 // wave-uniform -> s_load path
    float eac[CC], eab[CC];
#pragma unroll
    for (int k = 0; k < CC; ++k) {
      eac[k] = EAc[i * RS + k];
      eab[k] = EAb[i * RS + k];
    }
    const float4 ia = *(const float4*)(IA + i * 4);  // mAc, mAb, Acy, Aby
    const int yi = y[i];

    float sc = 0.f, sb = 0.f;
#pragma unroll
    for (int k = 0; k < CC; ++k) {
      sc = fmaf(eac[k], ebc[k], sc);
      sb = fmaf(eab[k], ebb[k], sb);
    }
    const float lse_c = ia.x + mBc + __logf(sc);
    const float lse_b = ia.y + mBb + __logf(sb);

    const float Bc_jyi = BcT[yi * NN + j];    // coalesced: per-lane j, uniform yi
    const float Bb_jyi = BbT[yi * NN + j];
    const float Ab_iyj = Abr[i * RS + yj];    // uniform row, per-lane col (1-2 lines)

    const float ce_pc = lse_c - ia.z - Bc_jyi;
    const float ce_pb = lse_b - ia.w - Bb_jyi;
    const float logp_yj = Ab_iyj + Bby - lse_b;
    const float gce = -logp_yj * __expf(GCE_Q_ * logp_yj);  // p^q = exp(q*logp)
    const float w = ce_pb * __builtin_amdgcn_rcpf(ce_pc + ce_pb + EPS_);
    out[(size_t)i * NN + j] = fmaf(w, ce_pc - gce, gce);    // w*ce + (1-w)*gce
  }
}

extern "C" void kernel_launch(void* const* d_in, const int* in_sizes, int n_in,
                              void* d_out, int out_size, void* d_ws, size_t ws_size,
                              hipStream_t stream) {
  const float* z_c = (const float*)d_in[0];
  const float* z_b = (const float*)d_in[1];
  const float* Wc  = (const float*)d_in[2];
  const float* bc  = (const float*)d_in[3];
  const float* Wb  = (const float*)d_in[4];
  const float* bb  = (const float*)d_in[5];
  const int*   y   = (const int*)d_in[6];
  float* out = (float*)d_out;
  float* ws  = (float*)d_ws;

  prep_kernel<<<dim3(512), dim3(256), 0, stream>>>(z_c, z_b, Wc, bc, Wb, bb, y, ws);
  pair_kernel<<<dim3(8, NN / ICH), dim3(256), 0, stream>>>(ws, y, out);
}

// Round 2
// 102.359 us; speedup vs baseline: 1.0135x; 1.0135x over previous
//
#include <hip/hip_runtime.h>

#define NN 2048
#define DD 1024
#define CC 10
#define RS 16          // j-side row stride (floats)
#define RREC 48        // i-side record stride (floats), 192 B
#define ICH 8          // i's per pair_kernel block
#define J2 2           // j's per pair_kernel thread
#define GCE_Q_ 0.7f
#define EPS_ 1e-8f

// workspace layout (float offsets)
// IREC [2048][48]: [0..9]=exp(Ac-mAc), [10..19]=exp(Ab-mAb), [20..29]=raw Ab row,
//                  [30..31]=pad, [32..35]={mAc-Ac[yi], mAb-Ab[yi], mAb, bits(y[i])}
#define OFF_IREC 0
#define OFF_EBc 98304    // [2048][16] exp(Bc - mBc)
#define OFF_EBb 131072   // [2048][16] exp(Bb - mBb)
#define OFF_JS  163840   // [2048][4] {mBc, mBb, Bb[j,yj]-mBb, 0}
#define OFF_BcT 172032   // [10][2048] raw Bc transposed
#define OFF_BbT 192512   // [10][2048] raw Bb transposed
// total 212992 floats = 851968 bytes

__device__ __forceinline__ float dpp_xor1_add(float x) {
  int xi = __float_as_int(x);
  int s = __builtin_amdgcn_update_dpp(xi, xi, 0xB1, 0xF, 0xF, false); // quad_perm[1,0,3,2]
  return x + __int_as_float(s);
}
__device__ __forceinline__ float dpp_xor2_add(float x) {
  int xi = __float_as_int(x);
  int s = __builtin_amdgcn_update_dpp(xi, xi, 0x4E, 0xF, 0xF, false); // quad_perm[2,3,0,1]
  return x + __int_as_float(s);
}

// ---------------------------------------------------------------------------
// Kernel 1: four skinny GEMMs ([4096 rows] x D=1024 -> 20 outputs/row) with
// W in registers + DPP quad reduction + softmax-prep epilogue.
// Rows 0..2047 = z_c (bias folded in), rows 2048..4095 = z_b.
// ---------------------------------------------------------------------------
__global__ __launch_bounds__(256) void prep_kernel(
    const float* __restrict__ z_c, const float* __restrict__ z_b,
    const float* __restrict__ Wc, const float* __restrict__ bc,
    const float* __restrict__ Wb, const float* __restrict__ bb,
    const int* __restrict__ y, float* __restrict__ ws)
{
  const int t = threadIdx.x;
  const int d0 = t * 4;

  float4 wcr[CC], wbr[CC];
#pragma unroll
  for (int k = 0; k < CC; ++k) {
    wcr[k] = *(const float4*)(Wc + k * DD + d0);
    wbr[k] = *(const float4*)(Wb + k * DD + d0);
  }

  const int rowBase = blockIdx.x * 8;          // 512 blocks x 8 rows = 4096
  const bool isB = rowBase >= NN;
  const float* __restrict__ z = isB ? z_b : z_c;
  const int r0 = isB ? (rowBase - NN) : rowBase;

  __shared__ float red[8][64][20];  // 40 KB
  __shared__ float sums[8][20];

  float4 zv = *(const float4*)(z + (size_t)r0 * DD + d0);
  for (int rr = 0; rr < 8; ++rr) {
    float4 zn = zv;
    if (rr < 7) zn = *(const float4*)(z + (size_t)(r0 + rr + 1) * DD + d0);

    float pc[CC], pb[CC];
#pragma unroll
    for (int k = 0; k < CC; ++k) {
      pc[k] = fmaf(zv.x, wcr[k].x, fmaf(zv.y, wcr[k].y, fmaf(zv.z, wcr[k].z, zv.w * wcr[k].w)));
      pb[k] = fmaf(zv.x, wbr[k].x, fmaf(zv.y, wbr[k].y, fmaf(zv.z, wbr[k].z, zv.w * wbr[k].w)));
    }
    // quad reduction on the VALU pipe (DPP), not the LDS pipe
#pragma unroll
    for (int k = 0; k < CC; ++k) { pc[k] = dpp_xor1_add(pc[k]); pb[k] = dpp_xor1_add(pb[k]); }
#pragma unroll
    for (int k = 0; k < CC; ++k) { pc[k] = dpp_xor2_add(pc[k]); pb[k] = dpp_xor2_add(pb[k]); }

    if ((t & 3) == 0) {
      float* dst = &red[rr][t >> 2][0];
#pragma unroll
      for (int k = 0; k < CC; ++k) { dst[k] = pc[k]; dst[CC + k] = pb[k]; }
    }
    zv = zn;
  }
  __syncthreads();

  // phase 2: 160 threads, one (row, output) each: reduce the 64 partials
  if (t < 160) {
    const int rr = t / 20;
    const int kk = t % 20;
    float s0 = 0.f, s1 = 0.f, s2 = 0.f, s3 = 0.f;
#pragma unroll
    for (int p = 0; p < 64; p += 4) {
      s0 += red[rr][p + 0][kk];
      s1 += red[rr][p + 1][kk];
      s2 += red[rr][p + 2][kk];
      s3 += red[rr][p + 3][kk];
    }
    float s = (s0 + s1) + (s2 + s3);
    if (!isB) s += (kk < CC) ? bc[kk] : bb[kk - CC];  // fold bias into i-side
    sums[rr][kk] = s;
  }
  __syncthreads();

  // phase 3: per-row softmax prep + stores
  if (t < 160) {
    const int rr = t / 20;
    const int kk = t % 20;
    const int head = kk / CC;
    const int k = kk % CC;
    const int row = r0 + rr;
    float m = -1e30f;
#pragma unroll
    for (int q = 0; q < CC; ++q) m = fmaxf(m, sums[rr][head * CC + q]);
    const float v = sums[rr][kk];
    const float e = __expf(v - m);
    float* rec = ws + OFF_IREC + row * RREC;
    if (!isB) {
      if (head == 0) {
        rec[k] = e;
      } else {
        rec[10 + k] = e;
        rec[20 + k] = v;                      // raw Ab row for y[j] gather
      }
    } else {
      if (head == 0) {
        ws[OFF_EBc + row * RS + k] = e;
        ws[OFF_BcT + k * NN + row] = v;       // transposed raw Bc
      } else {
        ws[OFF_EBb + row * RS + k] = e;
        ws[OFF_BbT + k * NN + row] = v;       // transposed raw Bb
      }
    }
    if (kk == 0) {
      const int yr = y[row];
      float m0 = -1e30f, m1 = -1e30f;
#pragma unroll
      for (int q = 0; q < CC; ++q) {
        m0 = fmaxf(m0, sums[rr][q]);
        m1 = fmaxf(m1, sums[rr][CC + q]);
      }
      if (!isB) {
        *(float4*)(rec + 32) = make_float4(m0 - sums[rr][yr],
                                           m1 - sums[rr][CC + yr],
                                           m1, __int_as_float(yr));
      } else {
        *(float4*)(ws + OFF_JS + row * 4) = make_float4(m0, m1,
                                                        sums[rr][CC + yr] - m1, 0.f);
      }
    }
  }
}

// ---------------------------------------------------------------------------
// Kernel 2: per-pair loss. Thread owns TWO j's (j-side exp rows in VGPRs),
// loops over ICH uniform i's (packed 192-B record via scalar loads).
// float2 gathers + float2 coalesced stores.
// ---------------------------------------------------------------------------
__global__ __launch_bounds__(256) void pair_kernel(
    const float* __restrict__ ws, const int* __restrict__ y,
    float* __restrict__ out)
{
  const float* __restrict__ EBc = ws + OFF_EBc;
  const float* __restrict__ EBb = ws + OFF_EBb;
  const float* __restrict__ JS  = ws + OFF_JS;
  const float* __restrict__ BcT = ws + OFF_BcT;
  const float* __restrict__ BbT = ws + OFF_BbT;

  const int j0 = (blockIdx.x * 256 + threadIdx.x) * J2;

  float ebc[J2][CC], ebb[J2][CC];
  float4 js[J2];
  int yj[J2];
#pragma unroll
  for (int jj = 0; jj < J2; ++jj) {
#pragma unroll
    for (int k = 0; k < CC; ++k) {
      ebc[jj][k] = EBc[(j0 + jj) * RS + k];
      ebb[jj][k] = EBb[(j0 + jj) * RS + k];
    }
    js[jj] = *(const float4*)(JS + (j0 + jj) * 4);
    yj[jj] = y[j0 + jj];
  }

  const int iBase = __builtin_amdgcn_readfirstlane(blockIdx.y * ICH);
#pragma unroll 2
  for (int ii = 0; ii < ICH; ++ii) {
    const int i = iBase + ii;                 // wave-uniform -> s_load path
    const float* __restrict__ rec = ws + OFF_IREC + i * RREC;
    float eac[CC], eab[CC];
#pragma unroll
    for (int k = 0; k < CC; ++k) { eac[k] = rec[k]; eab[k] = rec[10 + k]; }
    const float4 ia = *(const float4*)(rec + 32); // a0, a1, mAb, bits(yi)
    const int yi = __float_as_int(ia.w);

    const float2 bcv = *(const float2*)(BcT + yi * NN + j0); // coalesced
    const float2 bbv = *(const float2*)(BbT + yi * NN + j0);

    float outv[J2];
#pragma unroll
    for (int jj = 0; jj < J2; ++jj) {
      float sc = 0.f, sb = 0.f;
#pragma unroll
      for (int k = 0; k < CC; ++k) {
        sc = fmaf(eac[k], ebc[jj][k], sc);
        sb = fmaf(eab[k], ebb[jj][k], sb);
      }
      const float lc = __logf(sc);
      const float lb = __logf(sb);
      const float bc_ = jj ? bcv.y : bcv.x;
      const float bb_ = jj ? bbv.y : bbv.x;
      const float ce_pc = ia.x + js[jj].x + lc - bc_;
      const float ce_pb = ia.y + js[jj].y + lb - bb_;
      const float logp  = rec[20 + yj[jj]] + js[jj].z - ia.z - lb;
      const float gce   = -logp * __expf(GCE_Q_ * logp);     // p^q = exp(q*logp)
      const float w     = ce_pb * __builtin_amdgcn_rcpf(ce_pc + ce_pb + EPS_);
      outv[jj] = fmaf(w, ce_pc - gce, gce);   // w*ce + (1-w)*gce
    }
    *(float2*)(out + (size_t)i * NN + j0) = make_float2(outv[0], outv[1]);
  }
}

extern "C" void kernel_launch(void* const* d_in, const int* in_sizes, int n_in,
                              void* d_out, int out_size, void* d_ws, size_t ws_size,
                              hipStream_t stream) {
  const float* z_c = (const float*)d_in[0];
  const float* z_b = (const float*)d_in[1];
  const float* Wc  = (const float*)d_in[2];
  const float* bc  = (const float*)d_in[3];
  const float* Wb  = (const float*)d_in[4];
  const float* bb  = (const float*)d_in[5];
  const int*   y   = (const int*)d_in[6];
  float* out = (float*)d_out;
  float* ws  = (float*)d_ws;

  prep_kernel<<<dim3(512), dim3(256), 0, stream>>>(z_c, z_b, Wc, bc, Wb, bb, y, ws);
  pair_kernel<<<dim3(NN / (256 * J2), NN / ICH), dim3(256), 0, stream>>>(ws, y, out);
}